// Round 2
// baseline (3067.170 us; speedup 1.0000x reference)
//
#include <hip/hip_runtime.h>
#include <stdint.h>

#define HH 256
#define WW 1216
#define BB 2
#define CC 64
#define IPIX (HH*WW)
#define NPIX (BB*IPIX)

__device__ __forceinline__ float bf2f(unsigned short u) {
    union { unsigned int i; float f; } v; v.i = ((unsigned int)u) << 16; return v.f;
}
__device__ __forceinline__ unsigned short f2bf(float f) {
    union { float f; unsigned int i; } v; v.f = f;
    unsigned int i = v.i;
    i += 0x7FFFu + ((i >> 16) & 1u);   // round-to-nearest-even
    return (unsigned short)(i >> 16);
}

// layer order: aff7(24), aff5(16), aff3(8), att7(6), att5(6), att3(6), att1(6), mask(6)

// 7x7 tap -> aff plane index (-1 = center, uses g1 with no aff factor)
constexpr int PLANE[49] = {
  0, 1, 2, 3, 4, 5, 6,
  7,24,25,26,27,28, 8,
  9,29,40,41,42,30,10,
 11,31,43,-1,44,32,12,
 13,33,45,46,47,34,14,
 15,35,36,37,38,39,16,
 17,18,19,20,21,22,23};
// 7x7 tap -> kernel class: 0='7', 1='5', 2='3', 3='1'
constexpr int KCLS[49] = {
 0,0,0,0,0,0,0,
 0,1,1,1,1,1,0,
 0,1,2,2,2,1,0,
 0,1,2,3,2,1,0,
 0,1,2,2,2,1,0,
 0,1,1,1,1,1,0,
 0,0,0,0,0,0,0};

struct WPtrs {
    const float* w[8];
    const float* s[8];
    const float* b[8];
};

// ---------------- K1: all 78 convbn channels, fused stats/sigmoid ----------------
template<int O>
__device__ __forceinline__ void conv_one(const unsigned short (*sf)[324], int ty, int tx,
        const float* __restrict__ wts, const float* __restrict__ sc,
        const float* __restrict__ bi, float* __restrict__ res) {
    float acc[O];
#pragma unroll
    for (int o = 0; o < O; o++) acc[o] = 0.f;
    for (int c = 0; c < CC; c++) {
        float f9[9];
#pragma unroll
        for (int k = 0; k < 9; k++) {
            f9[k] = bf2f(sf[c][(ty + k / 3) * 18 + tx + (k % 3)]);
        }
        const float* wc = wts + c * 9;   // uniform -> scalar loads
#pragma unroll
        for (int o = 0; o < O; o++) {
#pragma unroll
            for (int k = 0; k < 9; k++) acc[o] = fmaf(f9[k], wc[o * 576 + k], acc[o]);
        }
    }
#pragma unroll
    for (int o = 0; o < O; o++) res[o] = fmaf(acc[o], sc[o], bi[o]);
}

__device__ __forceinline__ float sigm(float x) { return 1.f / (1.f + __expf(-x)); }

__global__ __launch_bounds__(256) void k_conv(const float* __restrict__ feat,
        const float* __restrict__ d00, WPtrs wp,
        float* __restrict__ aff, float* __restrict__ att, float* __restrict__ maskp,
        float* __restrict__ st) {
    __shared__ unsigned short sf[CC][324];   // 18x18 halo tile, bf16 bits, 41.5 KB
    const int tid = threadIdx.x;
    const int tx = tid & 15, ty = tid >> 4;
    const int x0 = blockIdx.x * 16, y0 = blockIdx.y * 16, b = blockIdx.z;
    const float* fb = feat + (size_t)b * CC * IPIX;
    for (int idx = tid; idx < CC * 324; idx += 256) {
        int c = idx / 324;
        int rem = idx - c * 324;
        int r = rem / 18, col = rem - r * 18;
        int gy = y0 + r - 1, gx = x0 + col - 1;
        float v = 0.f;
        if (gy >= 0 && gy < HH && gx >= 0 && gx < WW) v = fb[(size_t)c * IPIX + gy * WW + gx];
        sf[c][rem] = f2bf(v);
    }
    __syncthreads();

    const int pix = b * IPIX + (y0 + ty) * WW + (x0 + tx);
    float res[24];
    float S7, T7, S5, T5, S3, T3;

    conv_one<24>(sf, ty, tx, wp.w[0], wp.s[0], wp.b[0], res);
    S7 = 0.f; T7 = 0.f;
#pragma unroll
    for (int o = 0; o < 24; o++) { aff[(size_t)o * NPIX + pix] = res[o]; S7 += fabsf(res[o]); T7 += res[o]; }

    conv_one<16>(sf, ty, tx, wp.w[1], wp.s[1], wp.b[1], res);
    S5 = 0.f; T5 = 0.f;
#pragma unroll
    for (int o = 0; o < 16; o++) { aff[(size_t)(24 + o) * NPIX + pix] = res[o]; S5 += fabsf(res[o]); T5 += res[o]; }

    conv_one<8>(sf, ty, tx, wp.w[2], wp.s[2], wp.b[2], res);
    S3 = 0.f; T3 = 0.f;
#pragma unroll
    for (int o = 0; o < 8; o++) { aff[(size_t)(40 + o) * NPIX + pix] = res[o]; S3 += fabsf(res[o]); T3 += res[o]; }

    conv_one<6>(sf, ty, tx, wp.w[3], wp.s[3], wp.b[3], res);
#pragma unroll
    for (int o = 0; o < 6; o++) att[(size_t)(0 + o) * NPIX + pix] = sigm(res[o]);

    conv_one<6>(sf, ty, tx, wp.w[4], wp.s[4], wp.b[4], res);
#pragma unroll
    for (int o = 0; o < 6; o++) att[(size_t)(6 + o) * NPIX + pix] = sigm(res[o]);

    conv_one<6>(sf, ty, tx, wp.w[5], wp.s[5], wp.b[5], res);
#pragma unroll
    for (int o = 0; o < 6; o++) att[(size_t)(12 + o) * NPIX + pix] = sigm(res[o]);

    conv_one<6>(sf, ty, tx, wp.w[6], wp.s[6], wp.b[6], res);
#pragma unroll
    for (int o = 0; o < 6; o++) att[(size_t)(18 + o) * NPIX + pix] = sigm(res[o]);

    conv_one<6>(sf, ty, tx, wp.w[7], wp.s[7], wp.b[7], res);
    float valid = (d00[pix] > 0.f) ? 1.f : 0.f;
#pragma unroll
    for (int o = 0; o < 6; o++) maskp[(size_t)o * NPIX + pix] = sigm(res[o]) * valid;

    st[(size_t)0 * NPIX + pix] = S7;
    st[(size_t)1 * NPIX + pix] = S5;
    st[(size_t)2 * NPIX + pix] = S3;
    st[(size_t)3 * NPIX + pix] = T7;
    st[(size_t)4 * NPIX + pix] = T5;
    st[(size_t)5 * NPIX + pix] = T3;
}

// ---------------- K3 (per iter): r_k = att_k/denom; p_k = r_k*dt; base = g0*d0 ----------------
__global__ __launch_bounds__(256) void k_iterA(const float* __restrict__ att, const float* __restrict__ st,
        const float* __restrict__ dt, const float* __restrict__ d0,
        float* __restrict__ pb, float* __restrict__ base, int it) {
    int g = blockIdx.x * blockDim.x + threadIdx.x;
    if (g >= NPIX) return;
    float a7 = att[(size_t)(0 + it) * NPIX + g];
    float a5 = att[(size_t)(6 + it) * NPIX + g];
    float a3 = att[(size_t)(12 + it) * NPIX + g];
    float a1 = att[(size_t)(18 + it) * NPIX + g];
    float S7 = st[(size_t)0 * NPIX + g], S5 = st[(size_t)1 * NPIX + g], S3 = st[(size_t)2 * NPIX + g];
    float T7 = st[(size_t)3 * NPIX + g], T5 = st[(size_t)4 * NPIX + g], T3 = st[(size_t)5 * NPIX + g];
    float denom = a7 * S7 + a5 * S5 + a3 * S3 + a1;   // > 0 since a1 = sigmoid > 0
    float inv = 1.f / denom;
    float r7 = a7 * inv, r5 = a5 * inv, r3 = a3 * inv, r1 = a1 * inv;
    float g0 = 1.f - (r7 * T7 + r5 * T5 + r3 * T3 + r1);
    float dtv = dt[g];
    pb[(size_t)0 * NPIX + g] = r7 * dtv;
    pb[(size_t)1 * NPIX + g] = r5 * dtv;
    pb[(size_t)2 * NPIX + g] = r3 * dtv;
    pb[(size_t)3 * NPIX + g] = r1 * dtv;
    base[g] = g0 * d0[g];
}

// ---------------- K4 (per iter): 49-tap gather + mask blend ----------------
__global__ __launch_bounds__(256) void k_iterB(const float* __restrict__ aff, const float* __restrict__ pb,
        const float* __restrict__ base, const float* __restrict__ maskp,
        const float* __restrict__ d00,
        float* __restrict__ dtn, int it) {
    __shared__ float sp[4][14 * 38];   // 8+6 rows x 32+6 cols halo tile of p-planes
    const int tid = threadIdx.x;
    const int tx = tid & 31, ty = tid >> 5;
    const int x0 = blockIdx.x * 32, y0 = blockIdx.y * 8, b = blockIdx.z;
    const int ib = b * IPIX;
    for (int idx = tid; idx < 14 * 38; idx += 256) {
        int r = idx / 38, col = idx - r * 38;
        int gy = y0 + r - 3, gx = x0 + col - 3;
        bool inb = (gy >= 0) && (gy < HH) && (gx >= 0) && (gx < WW);
        int q = ib + gy * WW + gx;
#pragma unroll
        for (int k = 0; k < 4; k++) sp[k][idx] = inb ? pb[(size_t)k * NPIX + q] : 0.f;
    }
    __syncthreads();

    const int y = y0 + ty, x = x0 + tx;
    const int pix = ib + y * WW + x;
    float acc = 0.f;
#pragma unroll
    for (int t = 0; t < 49; t++) {
        const int dy = 3 - t / 7, dx = 3 - (t % 7);
        float pv = sp[KCLS[t]][(ty + dy + 3) * 38 + (tx + dx + 3)];
        if (PLANE[t] < 0) {
            acc += pv;
        } else {
            int qy = y + dy, qx = x + dx;
            bool inb = (qy >= 0) && (qy < HH) && (qx >= 0) && (qx < WW);
            float a = inb ? aff[(size_t)PLANE[t] * NPIX + ib + qy * WW + qx] : 0.f;
            acc = fmaf(a, pv, acc);
        }
    }
    float dtv = acc + base[pix];
    float m = maskp[(size_t)it * NPIX + pix];
    float d00v = d00[pix];
    dtv = m * d00v + (1.f - m) * dtv;
    dtn[pix] = dtv;
}

// ---------------- launch ----------------
extern "C" void kernel_launch(void* const* d_in, const int* in_sizes, int n_in,
                              void* d_out, int out_size, void* d_ws, size_t ws_size,
                              hipStream_t stream) {
    const float* feat = (const float*)d_in[0];
    const float* d0   = (const float*)d_in[1];
    const float* d00  = (const float*)d_in[2];
    WPtrs wp;
    for (int l = 0; l < 8; l++) {
        wp.w[l] = (const float*)d_in[3 + 3 * l];
        wp.s[l] = (const float*)d_in[4 + 3 * l];
        wp.b[l] = (const float*)d_in[5 + 3 * l];
    }
    float* ws    = (float*)d_ws;
    float* aff   = ws;                         // 48 planes
    float* att   = ws + (size_t)48 * NPIX;     // 24 planes
    float* maskp = ws + (size_t)72 * NPIX;     // 6 planes
    float* st    = ws + (size_t)78 * NPIX;     // 6 planes: S7,S5,S3,T7,T5,T3
    float* pb    = ws + (size_t)84 * NPIX;     // 4 planes: p7,p5,p3,p1
    float* base  = ws + (size_t)88 * NPIX;     // 1 plane
    float* dtA   = ws + (size_t)89 * NPIX;     // 1 plane (ping)
    float* dtB   = (float*)d_out;              // pong = d_out (fully overwritten before reads)

    hipLaunchKernelGGL(k_conv, dim3(WW / 16, HH / 16, BB), dim3(256), 0, stream,
                       feat, d00, wp, aff, att, maskp, st);
    // it0: d0 -> dtA; it1: dtA -> d_out; it2: d_out -> dtA; ... it5: dtA -> d_out
    const float* cur = d0;
    for (int it = 0; it < 6; ++it) {
        float* nxt = (it & 1) ? dtB : dtA;
        if (it == 5) nxt = dtB;  // final lands in d_out
        hipLaunchKernelGGL(k_iterA, dim3(NPIX / 256), dim3(256), 0, stream,
                           att, st, cur, d0, pb, base, it);
        hipLaunchKernelGGL(k_iterB, dim3(WW / 32, HH / 8, BB), dim3(256), 0, stream,
                           aff, pb, base, maskp, d00, nxt, it);
        cur = nxt;
    }
}

// Round 3
// 869.078 us; speedup vs baseline: 3.5292x; 3.5292x over previous
//
#include <hip/hip_runtime.h>
#include <stdint.h>

#define HH 256
#define WW 1216
#define BB 2
#define CC 64
#define IPIX (HH*WW)
#define NPIX (BB*IPIX)

typedef __attribute__((ext_vector_type(8))) __bf16 bf16x8;
typedef __attribute__((ext_vector_type(4))) float floatx4;

__device__ __forceinline__ float sigm(float x) { return 1.f / (1.f + __expf(-x)); }

// layer order: aff7(24), aff5(16), aff3(8), att7(6), att5(6), att3(6), att1(6), mask(6)
// global output channel m: 0..23 aff7, 24..39 aff5, 40..47 aff3, 48..53 att7,
// 54..59 att5, 60..65 att3, 66..71 att1, 72..77 mask, 78..79 zero-pad
constexpr int LSTART_H[9] = {0,24,40,48,54,60,66,72,78};

// 7x7 tap -> aff plane index (-1 = center, uses g1 with no aff factor)
constexpr int PLANE[49] = {
  0, 1, 2, 3, 4, 5, 6,
  7,24,25,26,27,28, 8,
  9,29,40,41,42,30,10,
 11,31,43,-1,44,32,12,
 13,33,45,46,47,34,14,
 15,35,36,37,38,39,16,
 17,18,19,20,21,22,23};
// 7x7 tap -> kernel class: 0='7', 1='5', 2='3', 3='1'
constexpr int KCLS[49] = {
 0,0,0,0,0,0,0,
 0,1,1,1,1,1,0,
 0,1,2,2,2,1,0,
 0,1,2,3,2,1,0,
 0,1,2,2,2,1,0,
 0,1,1,1,1,1,0,
 0,0,0,0,0,0,0};

struct WPtrs {
    const float* w[8];
    const float* s[8];
    const float* b[8];
};

// ---------------- K0: pack weights into MFMA A-fragment layout (bf16) ----------------
// A-frag for mfma_f32_16x16x32_bf16: lane l holds A[m = l&15][k = (l>>4)*8 + j], j=0..7.
// Global K order: k = tap*64 + c (tap-major). 18 K-steps of 32; M = 80 (5 tiles of 16).
// wpk[((kk*5 + t)*64 + lane)*8 + j]
__global__ void k_pack(WPtrs wp, __bf16* __restrict__ wpk,
                       float* __restrict__ s_all, float* __restrict__ b_all) {
    int idx = blockIdx.x * blockDim.x + threadIdx.x;
    if (idx < 18 * 5 * 64) {
        int kk = idx / (5 * 64);
        int r = idx - kk * 5 * 64;
        int t = r >> 6, lane = r & 63;
        int m = t * 16 + (lane & 15);
        int L = 0, o = 0;
        bool valid_m = (m < 78);
        if (valid_m) {
            for (int i = 0; i < 8; i++) if (m >= LSTART_H[i]) { L = i; o = m - LSTART_H[i]; }
        }
        __bf16 vals[8];
        for (int j = 0; j < 8; j++) {
            int k = kk * 32 + ((lane >> 4) * 8) + j;
            int tap = k >> 6, c = k & 63;
            float w = valid_m ? wp.w[L][(o * 64 + c) * 9 + tap] : 0.f;
            vals[j] = (__bf16)w;
        }
        for (int j = 0; j < 8; j++) wpk[(size_t)idx * 8 + j] = vals[j];
    }
    if (idx < 80) {
        int m = idx;
        float sv = 0.f, bv = 0.f;
        if (m < 78) {
            int L = 0, o = 0;
            for (int i = 0; i < 8; i++) if (m >= LSTART_H[i]) { L = i; o = m - LSTART_H[i]; }
            sv = wp.s[L][o]; bv = wp.b[L][o];
        }
        s_all[m] = sv; b_all[m] = bv;
    }
}

// ---------------- K1: conv as implicit GEMM via bf16 MFMA ----------------
// Block: 256 thr = 4 waves; pixel tile 64 wide x 4 high; wave w = row w, 4 N-frags of 16.
// LDS feature tile: [6 rows][66 cols][72 ch-stride] bf16 = 57024 B.
__global__ __launch_bounds__(256) void k_conv(const float* __restrict__ feat,
        const float* __restrict__ d00, const __bf16* __restrict__ wpk,
        const float* __restrict__ s_all, const float* __restrict__ b_all,
        float* __restrict__ aff, float* __restrict__ att, float* __restrict__ maskp,
        float* __restrict__ st) {
    __shared__ __bf16 sf[6 * 66 * 72];
    const int tid = threadIdx.x;
    const int x0 = blockIdx.x * 64, y0 = blockIdx.y * 4, b = blockIdx.z;
    const float* fb = feat + (size_t)b * CC * IPIX;

    // stage: order (row, c, x) -> global coalesced in x runs of 66
    for (int idx = tid; idx < 6 * 64 * 66; idx += 256) {
        int row = idx / (64 * 66);
        int rem = idx - row * 64 * 66;
        int c = rem / 66, x = rem - c * 66;
        int gy = y0 + row - 1, gx = x0 + x - 1;
        float v = 0.f;
        if (gy >= 0 && gy < HH && gx >= 0 && gx < WW) v = fb[(size_t)c * IPIX + gy * WW + gx];
        sf[(row * 66 + x) * 72 + c] = (__bf16)v;
    }
    __syncthreads();

    const int wave = tid >> 6, lane = tid & 63;
    const int n = lane & 15, g = lane >> 4;

    floatx4 acc[5][4];
#pragma unroll
    for (int t = 0; t < 5; t++)
#pragma unroll
        for (int q = 0; q < 4; q++) acc[t][q] = (floatx4)(0.f);

#pragma unroll 2
    for (int kk = 0; kk < 18; kk++) {
        const int tap = kk >> 1;
        const int dy = tap / 3 - 1, dx = tap % 3 - 1;
        const int c0 = (kk & 1) * 32 + g * 8;
        // B-frags: n = lane&15 (pixel), k = g*8+j (channel)
        bf16x8 bfr[4];
        const int rowb = wave + 1 + dy;
        const int colb = 1 + dx + n;
#pragma unroll
        for (int q = 0; q < 4; q++) {
            bfr[q] = *(const bf16x8*)(sf + ((rowb * 66) + colb + q * 16) * 72 + c0);
        }
        // A-frags from packed weights (L2-resident)
        bf16x8 afr[5];
        const __bf16* wp0 = wpk + ((size_t)(kk * 5) * 64 + lane) * 8;
#pragma unroll
        for (int t = 0; t < 5; t++) afr[t] = *(const bf16x8*)(wp0 + (size_t)t * 64 * 8);
#pragma unroll
        for (int t = 0; t < 5; t++)
#pragma unroll
            for (int q = 0; q < 4; q++)
                acc[t][q] = __builtin_amdgcn_mfma_f32_16x16x32_bf16(afr[t], bfr[q], acc[t][q], 0, 0, 0);
    }

    // epilogue: m = t*16 + 4*g + reg, pixel = pix_base + q*16
    const int pix_base = b * IPIX + (y0 + wave) * WW + x0 + n;
    float p7[4] = {0,0,0,0}, t7[4] = {0,0,0,0};
    float p5[4] = {0,0,0,0}, t5[4] = {0,0,0,0};
    float p3[4] = {0,0,0,0}, t3[4] = {0,0,0,0};
    float validq[4];
#pragma unroll
    for (int q = 0; q < 4; q++) validq[q] = (d00[pix_base + q * 16] > 0.f) ? 1.f : 0.f;

#pragma unroll
    for (int t = 0; t < 5; t++) {
        const floatx4 sv = *(const floatx4*)(s_all + t * 16 + 4 * g);
        const floatx4 bv = *(const floatx4*)(b_all + t * 16 + 4 * g);
#pragma unroll
        for (int q = 0; q < 4; q++) {
            const int pixq = pix_base + q * 16;
#pragma unroll
            for (int reg = 0; reg < 4; reg++) {
                const int m = t * 16 + 4 * g + reg;
                const float v = fmaf(acc[t][q][reg], sv[reg], bv[reg]);
                if (m < 24)                { p7[q] += fabsf(v); t7[q] += v; }
                else if (m < 40)           { p5[q] += fabsf(v); t5[q] += v; }
                else if (m < 48)           { p3[q] += fabsf(v); t3[q] += v; }
                if (m < 48)      aff[(size_t)m * NPIX + pixq] = v;
                else if (m < 72) att[(size_t)(m - 48) * NPIX + pixq] = sigm(v);
                else if (m < 78) maskp[(size_t)(m - 72) * NPIX + pixq] = sigm(v) * validq[q];
            }
        }
    }
    // butterfly over g (lanes n, n+16, n+32, n+48) -> per-pixel stats
#pragma unroll
    for (int q = 0; q < 4; q++) {
        p7[q] += __shfl_xor(p7[q], 16); p7[q] += __shfl_xor(p7[q], 32);
        t7[q] += __shfl_xor(t7[q], 16); t7[q] += __shfl_xor(t7[q], 32);
        p5[q] += __shfl_xor(p5[q], 16); p5[q] += __shfl_xor(p5[q], 32);
        t5[q] += __shfl_xor(t5[q], 16); t5[q] += __shfl_xor(t5[q], 32);
        p3[q] += __shfl_xor(p3[q], 16); p3[q] += __shfl_xor(p3[q], 32);
        t3[q] += __shfl_xor(t3[q], 16); t3[q] += __shfl_xor(t3[q], 32);
    }
    if (g == 0) {
#pragma unroll
        for (int q = 0; q < 4; q++) {
            const int pixq = pix_base + q * 16;
            st[(size_t)0 * NPIX + pixq] = p7[q];
            st[(size_t)1 * NPIX + pixq] = p5[q];
            st[(size_t)2 * NPIX + pixq] = p3[q];
            st[(size_t)3 * NPIX + pixq] = t7[q];
            st[(size_t)4 * NPIX + pixq] = t5[q];
            st[(size_t)5 * NPIX + pixq] = t3[q];
        }
    }
}

// ---------------- K3 (per iter): r_k = att_k/denom; p_k = r_k*dt; base = g0*d0 ----------------
__global__ __launch_bounds__(256) void k_iterA(const float* __restrict__ att, const float* __restrict__ st,
        const float* __restrict__ dt, const float* __restrict__ d0,
        float* __restrict__ pb, float* __restrict__ base, int it) {
    int g = blockIdx.x * blockDim.x + threadIdx.x;
    if (g >= NPIX) return;
    float a7 = att[(size_t)(0 + it) * NPIX + g];
    float a5 = att[(size_t)(6 + it) * NPIX + g];
    float a3 = att[(size_t)(12 + it) * NPIX + g];
    float a1 = att[(size_t)(18 + it) * NPIX + g];
    float S7 = st[(size_t)0 * NPIX + g], S5 = st[(size_t)1 * NPIX + g], S3 = st[(size_t)2 * NPIX + g];
    float T7 = st[(size_t)3 * NPIX + g], T5 = st[(size_t)4 * NPIX + g], T3 = st[(size_t)5 * NPIX + g];
    float denom = a7 * S7 + a5 * S5 + a3 * S3 + a1;   // > 0 since a1 = sigmoid > 0
    float inv = 1.f / denom;
    float r7 = a7 * inv, r5 = a5 * inv, r3 = a3 * inv, r1 = a1 * inv;
    float g0 = 1.f - (r7 * T7 + r5 * T5 + r3 * T3 + r1);
    float dtv = dt[g];
    pb[(size_t)0 * NPIX + g] = r7 * dtv;
    pb[(size_t)1 * NPIX + g] = r5 * dtv;
    pb[(size_t)2 * NPIX + g] = r3 * dtv;
    pb[(size_t)3 * NPIX + g] = r1 * dtv;
    base[g] = g0 * d0[g];
}

// ---------------- K4 (per iter): 49-tap gather + mask blend ----------------
__global__ __launch_bounds__(256) void k_iterB(const float* __restrict__ aff, const float* __restrict__ pb,
        const float* __restrict__ base, const float* __restrict__ maskp,
        const float* __restrict__ d00,
        float* __restrict__ dtn, int it) {
    __shared__ float sp[4][14 * 38];   // 8+6 rows x 32+6 cols halo tile of p-planes
    const int tid = threadIdx.x;
    const int tx = tid & 31, ty = tid >> 5;
    const int x0 = blockIdx.x * 32, y0 = blockIdx.y * 8, b = blockIdx.z;
    const int ib = b * IPIX;
    for (int idx = tid; idx < 14 * 38; idx += 256) {
        int r = idx / 38, col = idx - r * 38;
        int gy = y0 + r - 3, gx = x0 + col - 3;
        bool inb = (gy >= 0) && (gy < HH) && (gx >= 0) && (gx < WW);
        int q = ib + gy * WW + gx;
#pragma unroll
        for (int k = 0; k < 4; k++) sp[k][idx] = inb ? pb[(size_t)k * NPIX + q] : 0.f;
    }
    __syncthreads();

    const int y = y0 + ty, x = x0 + tx;
    const int pix = ib + y * WW + x;
    float acc = 0.f;
#pragma unroll
    for (int t = 0; t < 49; t++) {
        const int dy = 3 - t / 7, dx = 3 - (t % 7);
        float pv = sp[KCLS[t]][(ty + dy + 3) * 38 + (tx + dx + 3)];
        if (PLANE[t] < 0) {
            acc += pv;
        } else {
            int qy = y + dy, qx = x + dx;
            bool inb = (qy >= 0) && (qy < HH) && (qx >= 0) && (qx < WW);
            float a = inb ? aff[(size_t)PLANE[t] * NPIX + ib + qy * WW + qx] : 0.f;
            acc = fmaf(a, pv, acc);
        }
    }
    float dtv = acc + base[pix];
    float m = maskp[(size_t)it * NPIX + pix];
    float d00v = d00[pix];
    dtv = m * d00v + (1.f - m) * dtv;
    dtn[pix] = dtv;
}

// ---------------- launch ----------------
extern "C" void kernel_launch(void* const* d_in, const int* in_sizes, int n_in,
                              void* d_out, int out_size, void* d_ws, size_t ws_size,
                              hipStream_t stream) {
    const float* feat = (const float*)d_in[0];
    const float* d0   = (const float*)d_in[1];
    const float* d00  = (const float*)d_in[2];
    WPtrs wp;
    for (int l = 0; l < 8; l++) {
        wp.w[l] = (const float*)d_in[3 + 3 * l];
        wp.s[l] = (const float*)d_in[4 + 3 * l];
        wp.b[l] = (const float*)d_in[5 + 3 * l];
    }
    float* ws    = (float*)d_ws;
    float* aff   = ws;                         // 48 planes
    float* att   = ws + (size_t)48 * NPIX;     // 24 planes
    float* maskp = ws + (size_t)72 * NPIX;     // 6 planes
    float* st    = ws + (size_t)78 * NPIX;     // 6 planes: S7,S5,S3,T7,T5,T3
    float* pb    = ws + (size_t)84 * NPIX;     // 4 planes: p7,p5,p3,p1
    float* base  = ws + (size_t)88 * NPIX;     // 1 plane
    float* dtA   = ws + (size_t)89 * NPIX;     // 1 plane (ping)
    __bf16* wpk  = (__bf16*)(ws + (size_t)90 * NPIX);   // 92160 B packed weights
    float* s_all = ws + (size_t)90 * NPIX + 23040;      // 80 fp32
    float* b_all = s_all + 80;                           // 80 fp32
    float* dtB   = (float*)d_out;              // pong = d_out (fully overwritten before reads)

    hipLaunchKernelGGL(k_pack, dim3(23), dim3(256), 0, stream, wp, wpk, s_all, b_all);
    hipLaunchKernelGGL(k_conv, dim3(WW / 64, HH / 4, BB), dim3(256), 0, stream,
                       feat, d00, wpk, s_all, b_all, aff, att, maskp, st);
    // it0: d0 -> dtA; it1: dtA -> d_out; it2: d_out -> dtA; ... it5: dtA -> d_out
    const float* cur = d0;
    for (int it = 0; it < 6; ++it) {
        float* nxt = (it & 1) ? dtB : dtA;
        if (it == 5) nxt = dtB;  // final lands in d_out
        hipLaunchKernelGGL(k_iterA, dim3(NPIX / 256), dim3(256), 0, stream,
                           att, st, cur, d0, pb, base, it);
        hipLaunchKernelGGL(k_iterB, dim3(WW / 32, HH / 8, BB), dim3(256), 0, stream,
                           aff, pb, base, maskp, d00, nxt, it);
        cur = nxt;
    }
}